// Round 11
// baseline (51.067 us; speedup 1.0000x reference)
//
#include <hip/hip_runtime.h>

#define D256 256
#define KT 8
#define S_SEQ 1024
#define OUTSEQ 512

typedef __attribute__((ext_vector_type(8))) short bf16x8;
typedef __attribute__((ext_vector_type(8))) unsigned short u16x8;
typedef __attribute__((ext_vector_type(4))) unsigned short u16x4;
typedef __attribute__((ext_vector_type(4))) float f32x4;

__device__ inline unsigned short f2bf(float f) {          // RNE fp32->bf16
  unsigned u = __float_as_uint(f);
  return (unsigned short)((u + 0x7fffu + ((u >> 16) & 1u)) >> 16);
}

__device__ inline bf16x8 ld8bf(const float* p) {          // load 8 fp32, pack bf16x8
  const float4 v0 = *(const float4*)p;
  const float4 v1 = *(const float4*)(p + 4);
  bf16x8 r;
  r[0] = (short)f2bf(v0.x); r[1] = (short)f2bf(v0.y);
  r[2] = (short)f2bf(v0.z); r[3] = (short)f2bf(v0.w);
  r[4] = (short)f2bf(v1.x); r[5] = (short)f2bf(v1.y);
  r[6] = (short)f2bf(v1.z); r[7] = (short)f2bf(v1.w);
  return r;
}

// ---------------- k_pre: one dispatch, three independent jobs ----------------
// blocks   0..127 : Azn — Zpre=x@M^T (MFMA, in-reg bf16 cvt) -> LN -> Zb fp32;
//                   rfeat=x@resW^T -> Bt[d][2048+k] bf16
// blocks 128..383 : PIt4[j][i] = {P[i][j], 1/p, cb2, 0}, p = i*256+j+2
// blocks 384..639 : LinkTb[t][s] = bf16( s<1024 ? Linker[s][t] : rLinker[s-1024][t] )
__global__ __launch_bounds__(256) void k_pre(const float* __restrict__ x,
                                             const float* __restrict__ M,
                                             const float* __restrict__ resW,
                                             const float* __restrict__ P,
                                             const float* __restrict__ Linker,
                                             const float* __restrict__ rLinker,
                                             const float* __restrict__ gamma,
                                             const float* __restrict__ beta,
                                             float4* __restrict__ PIt4,
                                             unsigned short* __restrict__ LinkTb,
                                             float* __restrict__ Zb,
                                             unsigned short* __restrict__ Bt) {
  __shared__ float smem[8224];          // 32.9 KB, aliased per path
  const int tid = threadIdx.x;
  const int blk = blockIdx.x;

  if (blk < 128) {
    // ---------------- Azn path ----------------
    float (*Zs)[D256] = (float(*)[D256])smem;
    float (*Rs)[D256] = (float(*)[D256])(smem + 4096);
    float* mu_s = smem + 8192;
    float* rs_s = smem + 8208;
    const int k0 = blk * 16;
    const int w = tid >> 6;
    const int l = tid & 63;
    const int m = l & 15, q = l >> 4;

    f32x4 aZ[4] = {}, aR[4] = {};
    const float* xrow = x + (size_t)(k0 + m) * D256;
    #pragma unroll
    for (int ks = 0; ks < 8; ++ks) {
      const bf16x8 a = ld8bf(xrow + ks * 32 + q * 8);
      #pragma unroll
      for (int cf = 0; cf < 4; ++cf) {
        const int o = w * 64 + cf * 16 + m;
        const bf16x8 bz = ld8bf(M    + (size_t)o * D256 + ks * 32 + q * 8);
        const bf16x8 br = ld8bf(resW + (size_t)o * D256 + ks * 32 + q * 8);
        aZ[cf] = __builtin_amdgcn_mfma_f32_16x16x32_bf16(a, bz, aZ[cf], 0, 0, 0);
        aR[cf] = __builtin_amdgcn_mfma_f32_16x16x32_bf16(a, br, aR[cf], 0, 0, 0);
      }
    }
    #pragma unroll
    for (int cf = 0; cf < 4; ++cf) {
      #pragma unroll
      for (int r = 0; r < 4; ++r) {
        Zs[q * 4 + r][w * 64 + cf * 16 + m] = aZ[cf][r];
        Rs[q * 4 + r][w * 64 + cf * 16 + m] = aR[cf][r];
      }
    }
    __syncthreads();

    // LN stats: wave w reduces rows {w, w+4, w+8, w+12}
    #pragma unroll
    for (int rr = w; rr < 16; rr += 4) {
      float s = 0.f, sq = 0.f;
      #pragma unroll
      for (int p = 0; p < 4; ++p) {
        const float v = Zs[rr][l + 64 * p];
        s += v;
        sq = fmaf(v, v, sq);
      }
      #pragma unroll
      for (int off = 32; off; off >>= 1) {
        s += __shfl_down(s, off);
        sq += __shfl_down(sq, off);
      }
      if (l == 0) {
        const float mu = s * (1.0f / 256.0f);
        const float var = sq * (1.0f / 256.0f) - mu * mu;
        mu_s[rr] = mu;
        rs_s[rr] = rsqrtf(var + 1e-5f);
      }
    }
    __syncthreads();

    // normalize -> Zb fp32; pack rfeat -> Bt bf16 transposed
    {
      const int t = tid;
      const float g = gamma[t], be = beta[t];
      u16x8 o0, o1;
      #pragma unroll
      for (int rr = 0; rr < 16; ++rr) {
        Zb[(size_t)(k0 + rr) * D256 + t] = (Zs[rr][t] - mu_s[rr]) * rs_s[rr] * g + be;
        const unsigned short rb = f2bf(Rs[rr][t]);
        if (rr < 8) o0[rr] = rb; else o1[rr - 8] = rb;
      }
      unsigned short* dst = Bt + (size_t)t * 4096 + 2048 + k0;
      *(u16x8*)dst = o0;
      *(u16x8*)(dst + 8) = o1;
    }
    return;
  }

  if (blk < 384) {
    // ---------------- PIt4 path ----------------
    const int j = blk - 128;
    const int t = tid;
    const float p = (float)(t * D256 + j + 2);
    const float ip = 1.0f / p;
    const float cb2 = 2.0f * __builtin_amdgcn_cosf(ip);   // v_cos takes revolutions
    PIt4[j * D256 + t] = make_float4(P[t * D256 + j], ip, cb2, 0.0f);
    return;
  }

  // ---------------- LinkTb transpose-pack path ----------------
  float (*tl)[65] = (float(*)[65])smem;                   // 64*65 floats
  const int tb = blk - 384;             // 0..255
  const int st = tb & 31;               // s-tile (64 rows)
  const int tt = tb >> 5;               // t-tile (64 cols)
  const int s0 = st * 64, t0 = tt * 64;
  const float* src = (s0 < 1024) ? (Linker + (size_t)s0 * OUTSEQ)
                                 : (rLinker + (size_t)(s0 - 1024) * OUTSEQ);
  {
    const int sy = tid >> 2, sx = tid & 3;
    #pragma unroll
    for (int c = 0; c < 4; ++c) {
      const int ci = sx + c * 4;
      const float4 v = *(const float4*)&src[sy * OUTSEQ + t0 + ci * 4];
      tl[ci * 4 + 0][sy] = v.x;
      tl[ci * 4 + 1][sy] = v.y;
      tl[ci * 4 + 2][sy] = v.z;
      tl[ci * 4 + 3][sy] = v.w;
    }
  }
  __syncthreads();
  {
    const int ty = tid >> 2, tx = tid & 3;
    u16x8 o0, o1;
    #pragma unroll
    for (int e = 0; e < 8; ++e) o0[e] = f2bf(tl[ty][tx * 16 + e]);
    #pragma unroll
    for (int e = 0; e < 8; ++e) o1[e] = f2bf(tl[ty][tx * 16 + 8 + e]);
    unsigned short* dst = LinkTb + (size_t)(t0 + ty) * 2048 + s0 + tx * 16;
    *(u16x8*)dst = o0;
    *(u16x8*)(dst + 8) = o1;
  }
}

// ---------------- k_B: cos-einsum, 16-long Chebyshev chains ----------------
// grid 4096 = (k-tile kt of 16 rows) x (i-group ig of 8); 256 thr = jg(32) x il(8)
// thread: i = ig*8+il, owns j in {jg + 32*jj}, chains over 16 k's.
// In-block jg-reduce in LDS, bf16-pack direct to Bt[i][k].
__global__ __launch_bounds__(256, 6) void k_B(const float* __restrict__ Zb,
                                              const float4* __restrict__ PIt4,
                                              unsigned short* __restrict__ Bt) {
  __shared__ float buf[5120];           // 20 KB
  const int tid = threadIdx.x;
  const int il = tid & 7;
  const int jg = tid >> 3;              // 0..31
  const int ig = blockIdx.x & 31;
  const int kt = blockIdx.x >> 5;
  const int i0 = ig * 8;
  const int k0 = kt * 16;
  const int i  = i0 + il;

  // stage Z tile: buf[j*20 + k] = Zb[k0+k][j]   (coalesced global reads)
  #pragma unroll
  for (int r = 0; r < 16; ++r)
    buf[tid * 20 + r] = Zb[(size_t)(k0 + r) * D256 + tid];
  __syncthreads();

  float acc[16] = {};
  const float kf0 = (float)k0;
  const float4* pip = PIt4 + i;
  #pragma unroll
  for (int jj = 0; jj < 8; ++jj) {
    const int j = jg + 32 * jj;                    // stride-32 j: bank-clean b128 reads
    const float4 pi = pip[(size_t)j * D256];       // {P, 1/p, cb2, 0}
    const float4 z0 = *(const float4*)&buf[j * 20 + 0];   // 8-lane broadcast groups
    const float4 z1 = *(const float4*)&buf[j * 20 + 4];
    const float4 z2 = *(const float4*)&buf[j * 20 + 8];
    const float4 z3 = *(const float4*)&buf[j * 20 + 12];
    const float a = kf0 * pi.y;
    float c0 = __builtin_amdgcn_cosf(__builtin_amdgcn_fractf(a)) * pi.x;       // P folded
    float c1 = __builtin_amdgcn_cosf(__builtin_amdgcn_fractf(a + pi.y)) * pi.x;
    acc[0] = fmaf(z0.x, c0, acc[0]);
    acc[1] = fmaf(z0.y, c1, acc[1]);
    float c2;
    c2 = fmaf(pi.z, c1, -c0); acc[2]  = fmaf(z0.z, c2, acc[2]);  c0 = c1; c1 = c2;
    c2 = fmaf(pi.z, c1, -c0); acc[3]  = fmaf(z0.w, c2, acc[3]);  c0 = c1; c1 = c2;
    c2 = fmaf(pi.z, c1, -c0); acc[4]  = fmaf(z1.x, c2, acc[4]);  c0 = c1; c1 = c2;
    c2 = fmaf(pi.z, c1, -c0); acc[5]  = fmaf(z1.y, c2, acc[5]);  c0 = c1; c1 = c2;
    c2 = fmaf(pi.z, c1, -c0); acc[6]  = fmaf(z1.z, c2, acc[6]);  c0 = c1; c1 = c2;
    c2 = fmaf(pi.z, c1, -c0); acc[7]  = fmaf(z1.w, c2, acc[7]);  c0 = c1; c1 = c2;
    c2 = fmaf(pi.z, c1, -c0); acc[8]  = fmaf(z2.x, c2, acc[8]);  c0 = c1; c1 = c2;
    c2 = fmaf(pi.z, c1, -c0); acc[9]  = fmaf(z2.y, c2, acc[9]);  c0 = c1; c1 = c2;
    c2 = fmaf(pi.z, c1, -c0); acc[10] = fmaf(z2.z, c2, acc[10]); c0 = c1; c1 = c2;
    c2 = fmaf(pi.z, c1, -c0); acc[11] = fmaf(z2.w, c2, acc[11]); c0 = c1; c1 = c2;
    c2 = fmaf(pi.z, c1, -c0); acc[12] = fmaf(z3.x, c2, acc[12]); c0 = c1; c1 = c2;
    c2 = fmaf(pi.z, c1, -c0); acc[13] = fmaf(z3.y, c2, acc[13]); c0 = c1; c1 = c2;
    c2 = fmaf(pi.z, c1, -c0); acc[14] = fmaf(z3.z, c2, acc[14]); c0 = c1; c1 = c2;
    c2 = fmaf(pi.z, c1, -c0); acc[15] = fmaf(z3.w, c2, acc[15]);
  }
  __syncthreads();                      // Z reads done; reuse buf as red

  #pragma unroll
  for (int k = 0; k < 16; ++k)
    buf[jg * 132 + k * 8 + il] = acc[k];   // pad-132: <=2-way write conflicts
  __syncthreads();

  float tv = 0.f;
  if (tid < 128) {                      // tid = k*8 + il
    #pragma unroll
    for (int g = 0; g < 32; ++g) tv += buf[g * 132 + tid];
  }
  __syncthreads();
  if (tid < 128) buf[(tid & 7) * 16 + (tid >> 3)] = tv;   // outT[il][k]
  __syncthreads();
  if (tid < 32) {
    const int iw = tid >> 2;
    const int kq = tid & 3;
    const float4 v = *(const float4*)&buf[iw * 16 + kq * 4];
    u16x4 o;
    o[0] = f2bf(v.x); o[1] = f2bf(v.y); o[2] = f2bf(v.z); o[3] = f2bf(v.w);
    *(u16x4*)(Bt + (size_t)(i0 + iw) * 4096 + k0 + kq * 4) = o;
  }
}

// ---------------- k_Cm: bf16 MFMA GEMM, full K, direct out ----------------
// grid 256 = rt(32: b2 x t-tile16) x ct(8); 256 thr = 4 waves, wave = K-quarter
// of the block's 32x32 output tile; in-block LDS reduce; write out directly.
__global__ __launch_bounds__(256) void k_Cm(const unsigned short* __restrict__ LinkTb,
                                            const unsigned short* __restrict__ Bt,
                                            float* __restrict__ out) {
  __shared__ float red[4][32][32];      // 16 KB
  const int bid = blockIdx.x;
  const int ct = bid & 7;
  const int rt = bid >> 3;              // 0..31
  const int b  = rt >> 4;
  const int t0 = (rt & 15) * 32;
  const int d0 = ct * 32;
  const int w  = threadIdx.x >> 6;
  const int l  = threadIdx.x & 63;
  const int m  = l & 15, q = l >> 4;
  const int s0 = w * 256;               // this wave's within-batch s chunk

  f32x4 acc00 = {}, acc01 = {}, acc10 = {}, acc11 = {};
  const unsigned short* Arow = LinkTb + (size_t)(t0 + m) * 2048;
  const unsigned short* Brow = Bt + (size_t)(d0 + m) * 4096;

  #pragma unroll
  for (int seg = 0; seg < 2; ++seg) {
    const int acol = seg * 1024 + s0 + q * 8;
    const int bcol = seg * 2048 + b * 1024 + s0 + q * 8;
    #pragma unroll
    for (int ks = 0; ks < 8; ++ks) {
      const bf16x8 a0 = *(const bf16x8*)(Arow + acol + ks * 32);
      const bf16x8 a1 = *(const bf16x8*)(Arow + 16 * 2048 + acol + ks * 32);
      const bf16x8 b0 = *(const bf16x8*)(Brow + bcol + ks * 32);
      const bf16x8 b1 = *(const bf16x8*)(Brow + 16 * 4096 + bcol + ks * 32);
      acc00 = __builtin_amdgcn_mfma_f32_16x16x32_bf16(a0, b0, acc00, 0, 0, 0);
      acc01 = __builtin_amdgcn_mfma_f32_16x16x32_bf16(a0, b1, acc01, 0, 0, 0);
      acc10 = __builtin_amdgcn_mfma_f32_16x16x32_bf16(a1, b0, acc10, 0, 0, 0);
      acc11 = __builtin_amdgcn_mfma_f32_16x16x32_bf16(a1, b1, acc11, 0, 0, 0);
    }
  }

  #pragma unroll
  for (int r = 0; r < 4; ++r) {
    red[w][q * 4 + r][m]           = acc00[r];
    red[w][q * 4 + r][16 + m]      = acc01[r];
    red[w][16 + q * 4 + r][m]      = acc10[r];
    red[w][16 + q * 4 + r][16 + m] = acc11[r];
  }
  __syncthreads();

  const int row = threadIdx.x >> 3;
  const int c4  = (threadIdx.x & 7) * 4;
  const float4 v0 = *(const float4*)&red[0][row][c4];
  const float4 v1 = *(const float4*)&red[1][row][c4];
  const float4 v2 = *(const float4*)&red[2][row][c4];
  const float4 v3 = *(const float4*)&red[3][row][c4];
  float4 s;
  s.x = v0.x + v1.x + v2.x + v3.x;
  s.y = v0.y + v1.y + v2.y + v3.y;
  s.z = v0.z + v1.z + v2.z + v3.z;
  s.w = v0.w + v1.w + v2.w + v3.w;
  *(float4*)&out[(size_t)(b * 512 + t0 + row) * D256 + d0 + c4] = s;
}

extern "C" void kernel_launch(void* const* d_in, const int* in_sizes, int n_in,
                              void* d_out, int out_size, void* d_ws, size_t ws_size,
                              hipStream_t stream) {
  const float* x       = (const float*)d_in[0];
  const float* M       = (const float*)d_in[1];
  const float* P       = (const float*)d_in[2];
  const float* Linker  = (const float*)d_in[3];
  const float* gamma   = (const float*)d_in[4];
  const float* beta    = (const float*)d_in[5];
  const float* resW    = (const float*)d_in[6];
  const float* rLinker = (const float*)d_in[7];
  float* out = (float*)d_out;

  char* ws = (char*)d_ws;
  float4*         PIt4   = (float4*)(ws);                           // 1 MB
  unsigned short* LinkTb = (unsigned short*)(ws + 1024 * 1024);     // 2 MB
  unsigned short* Bt     = (unsigned short*)(ws + 3072 * 1024);     // 2 MB
  float*          Zb     = (float*)(ws + 5120 * 1024);              // 2 MB

  hipLaunchKernelGGL(k_pre, dim3(640),  dim3(256), 0, stream,
                     x, M, resW, P, Linker, rLinker, gamma, beta,
                     PIt4, LinkTb, Zb, Bt);
  hipLaunchKernelGGL(k_B,   dim3(4096), dim3(256), 0, stream, Zb, PIt4, Bt);
  hipLaunchKernelGGL(k_Cm,  dim3(256),  dim3(256), 0, stream, LinkTb, Bt, out);
}